// Round 2
// baseline (236.132 us; speedup 1.0000x reference)
//
#include <hip/hip_runtime.h>

#define C_DIM 128
#define H_DIM 32

// fast tanh: tanh(x) = 1 - 2/(e^{2x}+1). Handles +-inf correctly
// (x>>0: e=inf -> rcp=0 -> 1; x<<0: e=0 -> 1-2 = -1).
__device__ __forceinline__ float tanh_fast(float x) {
    float e = __expf(2.0f * x);
    return 1.0f - 2.0f * __builtin_amdgcn_rcpf(e + 1.0f);
}

// Chebyshev -> monomial transform of coeffs, done once per launch.
// T0=1, T1=t, T2=2t^2-1, T3=4t^3-3t, T4=8t^4-8t^2+1
//   p(t) = e0 + e1 t + e2 t^2 + e3 t^3 + e4 t^4
//   e0 = c0 - c2 + c4; e1 = c1 - 3c3; e2 = 2c2 - 8c4; e3 = 4c3; e4 = 8c4
// e0 is folded into a per-output bias (sum over input channels).
__global__ void prep_kernel(const float* __restrict__ c1, const float* __restrict__ c2,
                            float* __restrict__ E1, float* __restrict__ bias1,
                            float* __restrict__ E2, float* __restrict__ bias2) {
    int tid = threadIdx.x;
    // E1[i*H+o] = {e1,e2,e3,e4} for layer 1
    for (int p = tid; p < C_DIM * H_DIM; p += 256) {
        const float* c = c1 + p * 5;
        float4 e;
        e.x = c[1] - 3.0f * c[3];
        e.y = 2.0f * c[2] - 8.0f * c[4];
        e.z = 4.0f * c[3];
        e.w = 8.0f * c[4];
        reinterpret_cast<float4*>(E1)[p] = e;
    }
    if (tid < H_DIM) {
        // bias1[o] = sum_i e0[i,o]
        float b = 0.0f;
        for (int i = 0; i < C_DIM; ++i) {
            const float* c = c1 + (i * H_DIM + tid) * 5;
            b += c[0] - c[2] + c[4];
        }
        bias1[tid] = b;
        // layer-2 monomial coeffs
        const float* c = c2 + tid * 5;
        float4 e;
        e.x = c[1] - 3.0f * c[3];
        e.y = 2.0f * c[2] - 8.0f * c[4];
        e.z = 4.0f * c[3];
        e.w = 8.0f * c[4];
        reinterpret_cast<float4*>(E2)[tid] = e;
    }
    __shared__ float s[H_DIM];
    if (tid < H_DIM) {
        const float* c = c2 + tid * 5;
        s[tid] = c[0] - c[2] + c[4];
    }
    __syncthreads();
    if (tid == 0) {
        float b = 0.0f;
        for (int h = 0; h < H_DIM; ++h) b += s[h];
        bias2[0] = b;
    }
}

__global__ __launch_bounds__(256) void fused_kernel(
        const float* __restrict__ PRV, const float* __restrict__ PR,
        const float* __restrict__ E1, const float* __restrict__ bias1,
        const float* __restrict__ E2, const float* __restrict__ bias2,
        const float* __restrict__ gamma, const float* __restrict__ beta,
        const float* __restrict__ alphap, float* __restrict__ out) {
    // 64 channels per pass staged in LDS: 64*32 float4 = 32 KB.
    // All compute-loop reads are wave-uniform -> LDS broadcast, no conflicts,
    // no scalar-L2 latency stalls (the R1 bottleneck: VALUBusy 30%).
    __shared__ float4 sE[64 * H_DIM];
    __shared__ float s_scale[256];

    const int tid = threadIdx.x;
    const int row = blockIdx.x * 256 + tid;

    float acc[H_DIM];
    #pragma unroll
    for (int o = 0; o < H_DIM; ++o) acc[o] = bias1[o];  // uniform -> s_load

    const float4* pr4 = reinterpret_cast<const float4*>(PR) + (size_t)row * (C_DIM / 4);

    #pragma unroll 1
    for (int pass = 0; pass < 2; ++pass) {
        // ---- stage this pass's 64 channels of coeffs into LDS (coalesced) ----
        const float4* src = reinterpret_cast<const float4*>(E1) + pass * 64 * H_DIM;
        #pragma unroll
        for (int j = 0; j < 8; ++j)
            sE[j * 256 + tid] = src[j * 256 + tid];
        __syncthreads();

        // ---- layer 1 partial: acc[o] += sum_{i in pass} sum_k e_k[i,o] t_i^k ----
        #pragma unroll 1
        for (int ii = 0; ii < 16; ++ii) {
            float4 p = pr4[pass * 16 + ii];
            float xs[4] = {p.x, p.y, p.z, p.w};
            #pragma unroll
            for (int e = 0; e < 4; ++e) {
                float t  = tanh_fast(xs[e]);
                float t2 = t * t;
                float t3 = t2 * t;
                float t4 = t2 * t2;
                const float4* Ei = &sE[(ii * 4 + e) * H_DIM];
                #pragma unroll
                for (int o = 0; o < H_DIM; ++o) {
                    float4 cx = Ei[o];  // uniform addr -> LDS broadcast
                    float a = acc[o];
                    a = fmaf(cx.x, t,  a);
                    a = fmaf(cx.y, t2, a);
                    a = fmaf(cx.z, t3, a);
                    a = fmaf(cx.w, t4, a);
                    acc[o] = a;
                }
            }
        }
        __syncthreads();
    }

    // ---- LayerNorm over H, then ReLU + layer-2 ChebyKAN -> sigmoid ----
    float mu = 0.0f;
    #pragma unroll
    for (int o = 0; o < H_DIM; ++o) mu += acc[o];
    mu *= (1.0f / H_DIM);
    float var = 0.0f;
    #pragma unroll
    for (int o = 0; o < H_DIM; ++o) {
        float d = acc[o] - mu;
        var = fmaf(d, d, var);
    }
    var *= (1.0f / H_DIM);
    float rs = rsqrtf(var + 1e-5f);

    float z = bias2[0];
    #pragma unroll
    for (int o = 0; o < H_DIM; ++o) {
        float h = fmaf((acc[o] - mu) * rs, gamma[o], beta[o]);
        h = fmaxf(h, 0.0f);
        float t  = tanh_fast(h);
        float t2 = t * t;
        float t3 = t2 * t;
        float t4 = t2 * t2;
        float4 cx = reinterpret_cast<const float4*>(E2)[o];
        z = fmaf(cx.x, t,  z);
        z = fmaf(cx.y, t2, z);
        z = fmaf(cx.z, t3, z);
        z = fmaf(cx.w, t4, z);
    }
    float attn  = __builtin_amdgcn_rcpf(1.0f + __expf(-z));
    float scale = fmaf(alphap[0], attn, 1.0f);

    // ---- coalesced output sweep: out = PRV * (1 + alpha*attn) ----
    s_scale[tid] = scale;
    __syncthreads();

    const size_t base = (size_t)blockIdx.x * 256 * (C_DIM / 4);
    const float4* prv4 = reinterpret_cast<const float4*>(PRV) + base;
    float4* out4 = reinterpret_cast<float4*>(out) + base;
    #pragma unroll 1
    for (int it = 0; it < C_DIM / 4; ++it) {
        int idx = it * 256 + tid;
        float sc = s_scale[idx >> 5];  // 32 float4 per row
        float4 v = prv4[idx];
        v.x *= sc; v.y *= sc; v.z *= sc; v.w *= sc;
        out4[idx] = v;
    }
}

extern "C" void kernel_launch(void* const* d_in, const int* in_sizes, int n_in,
                              void* d_out, int out_size, void* d_ws, size_t ws_size,
                              hipStream_t stream) {
    const float* PRV    = (const float*)d_in[0];
    const float* PR     = (const float*)d_in[1];
    const float* c1     = (const float*)d_in[2];
    const float* gamma  = (const float*)d_in[3];
    const float* beta   = (const float*)d_in[4];
    const float* c2     = (const float*)d_in[5];
    const float* alphap = (const float*)d_in[6];
    float* out = (float*)d_out;

    float* ws    = (float*)d_ws;
    float* E1    = ws;            // 128*32*4 = 16384 floats
    float* bias1 = ws + 16384;    // 32
    float* E2    = ws + 16416;    // 32*4 = 128
    float* bias2 = ws + 16544;    // 1

    const int N = in_sizes[0] / C_DIM;

    hipLaunchKernelGGL(prep_kernel, dim3(1), dim3(256), 0, stream,
                       c1, c2, E1, bias1, E2, bias2);
    hipLaunchKernelGGL(fused_kernel, dim3(N / 256), dim3(256), 0, stream,
                       PRV, PR, E1, bias1, E2, bias2, gamma, beta, alphap, out);
}

// Round 3
// 142.665 us; speedup vs baseline: 1.6552x; 1.6552x over previous
//
#include <hip/hip_runtime.h>

#define C_DIM 128
#define H_DIM 32

typedef __attribute__((ext_vector_type(8))) short bf16x8;
typedef __attribute__((ext_vector_type(4))) float f32x4;

// fast tanh: tanh(x) = 1 - 2/(e^{2x}+1). Handles +-inf correctly.
__device__ __forceinline__ float tanh_fast(float x) {
    float e = __expf(2.0f * x);
    return 1.0f - 2.0f * __builtin_amdgcn_rcpf(e + 1.0f);
}

// f32 -> bf16 RNE (inputs finite; no NaN path needed)
__device__ __forceinline__ short f2bf(float f) {
    unsigned u = __builtin_bit_cast(unsigned, f);
    u += 0x7fffu + ((u >> 16) & 1u);
    return (short)(u >> 16);
}

// Chebyshev -> monomial: p(t) = e0 + e1 t + e2 t^2 + e3 t^3 + e4 t^4
//   e0 = c0 - c2 + c4; e1 = c1 - 3c3; e2 = 2c2 - 8c4; e3 = 4c3; e4 = 8c4
// e0 folded into bias1. Layer-1 coeffs are packed DIRECTLY in MFMA
// B-fragment order as bf16: Bpack[kc][half][lane][j], where
//   col = half*16 + (lane&15), channel = kc*8 + 2*(lane>>4) + (j>>2),
//   power index p = j&3 -> e_{p+1}.
// The A-fragment builder in fused_kernel uses the IDENTICAL (k-slot -> channel,power)
// map, so any hardware k-permutation cancels (A/B layouts are symmetric).
__global__ void prep_kernel(const float* __restrict__ c1, const float* __restrict__ c2,
                            unsigned short* __restrict__ Bpack, float* __restrict__ bias1,
                            float* __restrict__ E2, float* __restrict__ bias2) {
    int tid = threadIdx.x;
    for (int idx = tid; idx < 16 * 2 * 64 * 8; idx += 256) {
        int kc = idx >> 10;
        int h  = (idx >> 9) & 1;
        int l  = (idx >> 3) & 63;
        int j  = idx & 7;
        int c   = kc * 8 + ((l >> 4) << 1) + (j >> 2);
        int col = h * 16 + (l & 15);
        int p   = j & 3;
        const float* cc = c1 + (c * H_DIM + col) * 5;
        float v;
        if (p == 0)      v = cc[1] - 3.0f * cc[3];
        else if (p == 1) v = 2.0f * cc[2] - 8.0f * cc[4];
        else if (p == 2) v = 4.0f * cc[3];
        else             v = 8.0f * cc[4];
        Bpack[idx] = (unsigned short)f2bf(v);
    }
    if (tid < H_DIM) {
        float b = 0.0f;
        for (int i = 0; i < C_DIM; ++i) {
            const float* cc = c1 + (i * H_DIM + tid) * 5;
            b += cc[0] - cc[2] + cc[4];
        }
        bias1[tid] = b;
        const float* cc = c2 + tid * 5;
        float4 e;
        e.x = cc[1] - 3.0f * cc[3];
        e.y = 2.0f * cc[2] - 8.0f * cc[4];
        e.z = 4.0f * cc[3];
        e.w = 8.0f * cc[4];
        reinterpret_cast<float4*>(E2)[tid] = e;
    }
    __shared__ float s[H_DIM];
    if (tid < H_DIM) {
        const float* cc = c2 + tid * 5;
        s[tid] = cc[0] - cc[2] + cc[4];
    }
    __syncthreads();
    if (tid == 0) {
        float b = 0.0f;
        for (int hh = 0; hh < H_DIM; ++hh) b += s[hh];
        bias2[0] = b;
    }
}

__global__ __launch_bounds__(256, 4) void fused_kernel(
        const float* __restrict__ PRV, const float* __restrict__ PR,
        const unsigned short* __restrict__ Bpack, const float* __restrict__ bias1,
        const float* __restrict__ E2, const float* __restrict__ bias2,
        const float* __restrict__ gamma, const float* __restrict__ beta,
        const float* __restrict__ alphap, float* __restrict__ out) {
    __shared__ short sB[16 * 2 * 64 * 8];   // 32 KB: B-frags in lane order
    __shared__ float s_scale[256];

    const int tid = threadIdx.x;
    // stage B fragments into LDS, coalesced (32 KB / 256 thr = 8 float4 each)
    {
        const float4* src = reinterpret_cast<const float4*>(Bpack);
        float4* dst = reinterpret_cast<float4*>(sB);
        #pragma unroll
        for (int j = 0; j < 8; ++j) dst[j * 256 + tid] = src[j * 256 + tid];
    }
    __syncthreads();

    const int wid  = tid >> 6;
    const int lane = tid & 63;
    const int g    = lane >> 4;   // k-group (channel pair selector)
    const int lr   = lane & 15;   // A-row within tile / C-col within half

    // wave owns 64 rows = 4 M-tiles of 16
    const float2* pr2 = reinterpret_cast<const float2*>(PR);
    const size_t rbase = (size_t)blockIdx.x * 256 + wid * 64 + lr;
    const float2* p0 = pr2 + (rbase +  0) * (C_DIM / 2) + g;
    const float2* p1 = pr2 + (rbase + 16) * (C_DIM / 2) + g;
    const float2* p2 = pr2 + (rbase + 32) * (C_DIM / 2) + g;
    const float2* p3 = pr2 + (rbase + 48) * (C_DIM / 2) + g;

    f32x4 acc[4][2];
    {
        float b0 = bias1[lr], b1 = bias1[16 + lr];
        #pragma unroll
        for (int t = 0; t < 4; ++t) {
            acc[t][0] = (f32x4){b0, b0, b0, b0};
            acc[t][1] = (f32x4){b1, b1, b1, b1};
        }
    }

    const bf16x8* sB8 = reinterpret_cast<const bf16x8*>(sB);

    // K-loop: 16 chunks of K=32 (= 8 channels x 4 powers)
    #pragma unroll 4
    for (int kc = 0; kc < 16; ++kc) {
        float2 x0 = p0[kc * 4];
        float2 x1 = p1[kc * 4];
        float2 x2 = p2[kc * 4];
        float2 x3 = p3[kc * 4];
        bf16x8 bf0 = sB8[(kc * 2 + 0) * 64 + lane];
        bf16x8 bf1 = sB8[(kc * 2 + 1) * 64 + lane];
        #define DO_TILE(T, X) { \
            float ta = tanh_fast(X.x), tb = tanh_fast(X.y); \
            float ta2 = ta * ta, tb2 = tb * tb; \
            bf16x8 af; \
            af[0] = f2bf(ta);       af[1] = f2bf(ta2); \
            af[2] = f2bf(ta2 * ta); af[3] = f2bf(ta2 * ta2); \
            af[4] = f2bf(tb);       af[5] = f2bf(tb2); \
            af[6] = f2bf(tb2 * tb); af[7] = f2bf(tb2 * tb2); \
            acc[T][0] = __builtin_amdgcn_mfma_f32_16x16x32_bf16(af, bf0, acc[T][0], 0, 0, 0); \
            acc[T][1] = __builtin_amdgcn_mfma_f32_16x16x32_bf16(af, bf1, acc[T][1], 0, 0, 0); }
        DO_TILE(0, x0)
        DO_TILE(1, x1)
        DO_TILE(2, x2)
        DO_TILE(3, x3)
        #undef DO_TILE
    }

    // ---- LayerNorm + ReLU + layer-2 ChebyKAN + sigmoid, per M-tile ----
    // C layout: col = h*16 + lr, row = g*4 + reg  (verified m89/m91)
    const float gam0 = gamma[lr], gam1 = gamma[16 + lr];
    const float bet0 = beta[lr],  bet1 = beta[16 + lr];
    const float4 e2a = reinterpret_cast<const float4*>(E2)[lr];
    const float4 e2b = reinterpret_cast<const float4*>(E2)[16 + lr];
    const float zb = bias2[0];
    const float alpha = alphap[0];

    #pragma unroll
    for (int t = 0; t < 4; ++t) {
        f32x4 a0 = acc[t][0], a1 = acc[t][1];
        float s[4], vs[4], z[4];
        #pragma unroll
        for (int r = 0; r < 4; ++r) s[r] = a0[r] + a1[r];
        #pragma unroll
        for (int m = 1; m <= 8; m <<= 1) {
            #pragma unroll
            for (int r = 0; r < 4; ++r) s[r] += __shfl_xor(s[r], m, 64);
        }
        #pragma unroll
        for (int r = 0; r < 4; ++r) {
            float mu = s[r] * (1.0f / 32.0f);
            float d0 = a0[r] - mu, d1 = a1[r] - mu;
            a0[r] = d0; a1[r] = d1;
            vs[r] = d0 * d0 + d1 * d1;
        }
        #pragma unroll
        for (int m = 1; m <= 8; m <<= 1) {
            #pragma unroll
            for (int r = 0; r < 4; ++r) vs[r] += __shfl_xor(vs[r], m, 64);
        }
        #pragma unroll
        for (int r = 0; r < 4; ++r) {
            float rs = rsqrtf(vs[r] * (1.0f / 32.0f) + 1e-5f);
            float h0 = fmaf(a0[r] * rs, gam0, bet0);
            float h1 = fmaf(a1[r] * rs, gam1, bet1);
            h0 = fmaxf(h0, 0.0f); h1 = fmaxf(h1, 0.0f);
            float t0 = tanh_fast(h0), t1 = tanh_fast(h1);
            float t02 = t0 * t0, t12 = t1 * t1;
            float zp = fmaf(e2a.x, t0, fmaf(e2a.y, t02,
                        fmaf(e2a.z, t02 * t0, e2a.w * (t02 * t02))));
            zp += fmaf(e2b.x, t1, fmaf(e2b.y, t12,
                    fmaf(e2b.z, t12 * t1, e2b.w * (t12 * t12))));
            z[r] = zp;
        }
        #pragma unroll
        for (int m = 1; m <= 8; m <<= 1) {
            #pragma unroll
            for (int r = 0; r < 4; ++r) z[r] += __shfl_xor(z[r], m, 64);
        }
        if (lr == 0) {
            #pragma unroll
            for (int r = 0; r < 4; ++r) {
                float attn = __builtin_amdgcn_rcpf(1.0f + __expf(-(z[r] + zb)));
                s_scale[wid * 64 + t * 16 + g * 4 + r] = fmaf(alpha, attn, 1.0f);
            }
        }
    }
    __syncthreads();

    // ---- coalesced gate sweep: out = PRV * (1 + alpha*attn) ----
    const size_t base = (size_t)blockIdx.x * 256 * (C_DIM / 4);
    const float4* prv4 = reinterpret_cast<const float4*>(PRV) + base;
    float4* out4 = reinterpret_cast<float4*>(out) + base;
    #pragma unroll 4
    for (int it = 0; it < C_DIM / 4; ++it) {
        int idx = it * 256 + tid;
        float sc = s_scale[idx >> 5];   // 32 float4 per row
        float4 v = prv4[idx];
        v.x *= sc; v.y *= sc; v.z *= sc; v.w *= sc;
        out4[idx] = v;
    }
}

extern "C" void kernel_launch(void* const* d_in, const int* in_sizes, int n_in,
                              void* d_out, int out_size, void* d_ws, size_t ws_size,
                              hipStream_t stream) {
    const float* PRV    = (const float*)d_in[0];
    const float* PR     = (const float*)d_in[1];
    const float* c1     = (const float*)d_in[2];
    const float* gamma  = (const float*)d_in[3];
    const float* beta   = (const float*)d_in[4];
    const float* c2     = (const float*)d_in[5];
    const float* alphap = (const float*)d_in[6];
    float* out = (float*)d_out;

    unsigned short* Bpack = (unsigned short*)d_ws;            // 32 KB bf16 frags
    float* wsf   = (float*)((char*)d_ws + 32768);
    float* bias1 = wsf;          // 32
    float* E2    = wsf + 32;     // 128 (32 x float4)
    float* bias2 = wsf + 160;    // 1

    const int N = in_sizes[0] / C_DIM;

    hipLaunchKernelGGL(prep_kernel, dim3(1), dim3(256), 0, stream,
                       c1, c2, Bpack, bias1, E2, bias2);
    hipLaunchKernelGGL(fused_kernel, dim3(N / 256), dim3(256), 0, stream,
                       PRV, PR, Bpack, bias1, E2, bias2, gamma, beta, alphap, out);
}

// Round 4
// 91.170 us; speedup vs baseline: 2.5900x; 1.5648x over previous
//
#include <hip/hip_runtime.h>
#include <hip/hip_bf16.h>

#define C_DIM 128
#define H_DIM 32

typedef __attribute__((ext_vector_type(8))) short bf16x8;
typedef __attribute__((ext_vector_type(4))) float f32x4;

// fast tanh: tanh(x) = 1 - 2/(e^{2x}+1). Handles +-inf correctly.
__device__ __forceinline__ float tanh_fast(float x) {
    float e = __expf(2.0f * x);
    return 1.0f - 2.0f * __builtin_amdgcn_rcpf(e + 1.0f);
}

// f32 -> bf16 RNE via library cast (compiler emits v_cvt_pk_bf16_f32 pairs)
__device__ __forceinline__ short f2bf(float f) {
    return __builtin_bit_cast(short, __float2bfloat16(f));
}

// Chebyshev -> monomial: p(t) = e0 + e1 t + e2 t^2 + e3 t^3 + e4 t^4
//   e0 = c0 - c2 + c4; e1 = c1 - 3c3; e2 = 2c2 - 8c4; e3 = 4c3; e4 = 8c4
// e0 folded into bias1 (summed over channels).
//
// Layer-1 coeffs packed directly in MFMA B-fragment order (bf16):
//   Bpack[kc][oh][lane][j]:
//     col     = oh*16 + (lane&15)
//     channel = (kc>>1)*16 + 4*(lane>>4) + 2*(kc&1) + (j>>2)
//     power   = (j&3) -> e_{p+1}
// The A-fragment builder uses the IDENTICAL (lane,j)->(channel,power) map,
// so any hardware k-permutation cancels (A/B fragment layouts are symmetric).
// This map makes each lane's per-kc2 A-input one aligned float4 of PR.
__global__ void prep_kernel(const float* __restrict__ c1, const float* __restrict__ c2,
                            unsigned short* __restrict__ Bpack, float* __restrict__ bias1,
                            float* __restrict__ E2, float* __restrict__ bias2) {
    const int tid = threadIdx.x;
    const int idx = blockIdx.x * 256 + tid;   // grid 64*256 = 16384 = one per element
    {
        int kc = idx >> 10;
        int oh = (idx >> 9) & 1;
        int l  = (idx >> 3) & 63;
        int j  = idx & 7;
        int g  = l >> 4;
        int kc2 = kc >> 1, kh = kc & 1;
        int c   = kc2 * 16 + 4 * g + 2 * kh + (j >> 2);
        int col = oh * 16 + (l & 15);
        int p   = j & 3;
        const float* cc = c1 + (c * H_DIM + col) * 5;
        float v = (p == 0) ? cc[1] - 3.0f * cc[3]
                : (p == 1) ? 2.0f * cc[2] - 8.0f * cc[4]
                : (p == 2) ? 4.0f * cc[3]
                           : 8.0f * cc[4];
        Bpack[idx] = (unsigned short)f2bf(v);
    }
    if (blockIdx.x == 0) {
        __shared__ float part[256];
        // bias1[o] = sum_i e0[i,o]; 8-way split over channel chunks
        const int o = tid & 31, ch = tid >> 5;
        float b = 0.0f;
        for (int i = ch * 16; i < ch * 16 + 16; ++i) {
            const float* cc = c1 + (i * H_DIM + o) * 5;
            b += cc[0] - cc[2] + cc[4];
        }
        part[tid] = b;
        __syncthreads();
        if (tid < 32) {
            float s = 0.0f;
            #pragma unroll
            for (int k = 0; k < 8; ++k) s += part[k * 32 + tid];
            bias1[tid] = s;
            const float* cc = c2 + tid * 5;
            float4 e;
            e.x = cc[1] - 3.0f * cc[3];
            e.y = 2.0f * cc[2] - 8.0f * cc[4];
            e.z = 4.0f * cc[3];
            e.w = 8.0f * cc[4];
            reinterpret_cast<float4*>(E2)[tid] = e;
        }
        __syncthreads();
        if (tid < 32) part[tid] = c2[tid * 5] - c2[tid * 5 + 2] + c2[tid * 5 + 4];
        __syncthreads();
        if (tid == 0) {
            float b2 = 0.0f;
            for (int h = 0; h < 32; ++h) b2 += part[h];
            bias2[0] = b2;
        }
    }
}

__global__ __launch_bounds__(256, 4) void fused_kernel(
        const float* __restrict__ PRV, const float* __restrict__ PR,
        const unsigned short* __restrict__ Bpack, const float* __restrict__ bias1,
        const float* __restrict__ E2, const float* __restrict__ bias2,
        const float* __restrict__ gamma, const float* __restrict__ beta,
        const float* __restrict__ alphap, float* __restrict__ out) {
    __shared__ short sB[16 * 2 * 64 * 8];   // 32 KB: B-frags in lane order
    __shared__ float s_scale[256];

    const int tid  = threadIdx.x;
    const int wid  = tid >> 6;
    const int lane = tid & 63;
    const int g    = lane >> 4;
    const int lr   = lane & 15;

    // per-lane PR pointers (float4 of 4 consecutive channels per kc2)
    const float4* pr4 = reinterpret_cast<const float4*>(PR);
    const size_t rbase = (size_t)blockIdx.x * 256 + wid * 64 + lr;
    const float4* q0 = pr4 + (rbase +  0) * (C_DIM / 4) + g;
    const float4* q1 = pr4 + (rbase + 16) * (C_DIM / 4) + g;
    const float4* q2 = pr4 + (rbase + 32) * (C_DIM / 4) + g;
    const float4* q3 = pr4 + (rbase + 48) * (C_DIM / 4) + g;

    // issue first PR loads before B-staging so HBM latency overlaps staging
    float4 xc0 = q0[0], xc1 = q1[0], xc2 = q2[0], xc3 = q3[0];

    // stage B fragments into LDS, coalesced (32 KB / 256 thr = 8 float4 each)
    {
        const float4* src = reinterpret_cast<const float4*>(Bpack);
        float4* dst = reinterpret_cast<float4*>(sB);
        #pragma unroll
        for (int j = 0; j < 8; ++j) dst[j * 256 + tid] = src[j * 256 + tid];
    }
    __syncthreads();

    f32x4 acc[4][2];
    {
        float b0 = bias1[lr], b1 = bias1[16 + lr];
        #pragma unroll
        for (int t = 0; t < 4; ++t) {
            acc[t][0] = (f32x4){b0, b0, b0, b0};
            acc[t][1] = (f32x4){b1, b1, b1, b1};
        }
    }

    const bf16x8* sB8 = reinterpret_cast<const bf16x8*>(sB);

    // K-loop: 8 chunks of K=64 (16 channels x 4 powers), depth-2 pipelined
    #pragma unroll 1
    for (int kc2 = 0; kc2 < 8; ++kc2) {
        const int nk = ((kc2 + 1) & 7) * 4;
        float4 xn0 = q0[nk], xn1 = q1[nk], xn2 = q2[nk], xn3 = q3[nk];
        bf16x8 be0 = sB8[(kc2 * 4 + 0) * 64 + lane];
        bf16x8 be1 = sB8[(kc2 * 4 + 1) * 64 + lane];
        bf16x8 bo0 = sB8[(kc2 * 4 + 2) * 64 + lane];
        bf16x8 bo1 = sB8[(kc2 * 4 + 3) * 64 + lane];
        #define DO_TILE(XC, T) { \
            float t0 = tanh_fast(XC.x), t1 = tanh_fast(XC.y); \
            float t2 = tanh_fast(XC.z), t3 = tanh_fast(XC.w); \
            float s0 = t0 * t0, s1 = t1 * t1, s2 = t2 * t2, s3 = t3 * t3; \
            bf16x8 ae, ao; \
            ae[0] = f2bf(t0); ae[1] = f2bf(s0); ae[2] = f2bf(s0 * t0); ae[3] = f2bf(s0 * s0); \
            ae[4] = f2bf(t1); ae[5] = f2bf(s1); ae[6] = f2bf(s1 * t1); ae[7] = f2bf(s1 * s1); \
            ao[0] = f2bf(t2); ao[1] = f2bf(s2); ao[2] = f2bf(s2 * t2); ao[3] = f2bf(s2 * s2); \
            ao[4] = f2bf(t3); ao[5] = f2bf(s3); ao[6] = f2bf(s3 * t3); ao[7] = f2bf(s3 * s3); \
            acc[T][0] = __builtin_amdgcn_mfma_f32_16x16x32_bf16(ae, be0, acc[T][0], 0, 0, 0); \
            acc[T][1] = __builtin_amdgcn_mfma_f32_16x16x32_bf16(ae, be1, acc[T][1], 0, 0, 0); \
            acc[T][0] = __builtin_amdgcn_mfma_f32_16x16x32_bf16(ao, bo0, acc[T][0], 0, 0, 0); \
            acc[T][1] = __builtin_amdgcn_mfma_f32_16x16x32_bf16(ao, bo1, acc[T][1], 0, 0, 0); }
        DO_TILE(xc0, 0)
        DO_TILE(xc1, 1)
        DO_TILE(xc2, 2)
        DO_TILE(xc3, 3)
        #undef DO_TILE
        xc0 = xn0; xc1 = xn1; xc2 = xn2; xc3 = xn3;
    }

    // ---- LayerNorm + ReLU + layer-2 ChebyKAN + sigmoid, per M-tile ----
    // C layout: col = oh*16 + lr, row = g*4 + reg  (verified m89/m91)
    const float gam0 = gamma[lr], gam1 = gamma[16 + lr];
    const float bet0 = beta[lr],  bet1 = beta[16 + lr];
    const float4 e2a = reinterpret_cast<const float4*>(E2)[lr];
    const float4 e2b = reinterpret_cast<const float4*>(E2)[16 + lr];
    const float zb = bias2[0];
    const float alpha = alphap[0];

    #pragma unroll
    for (int t = 0; t < 4; ++t) {
        f32x4 a0 = acc[t][0], a1 = acc[t][1];
        float s[4], vs[4], z[4];
        #pragma unroll
        for (int r = 0; r < 4; ++r) s[r] = a0[r] + a1[r];
        #pragma unroll
        for (int m = 1; m <= 8; m <<= 1) {
            #pragma unroll
            for (int r = 0; r < 4; ++r) s[r] += __shfl_xor(s[r], m, 64);
        }
        #pragma unroll
        for (int r = 0; r < 4; ++r) {
            float mu = s[r] * (1.0f / 32.0f);
            float d0 = a0[r] - mu, d1 = a1[r] - mu;
            a0[r] = d0; a1[r] = d1;
            vs[r] = d0 * d0 + d1 * d1;
        }
        #pragma unroll
        for (int m = 1; m <= 8; m <<= 1) {
            #pragma unroll
            for (int r = 0; r < 4; ++r) vs[r] += __shfl_xor(vs[r], m, 64);
        }
        #pragma unroll
        for (int r = 0; r < 4; ++r) {
            float rs = rsqrtf(vs[r] * (1.0f / 32.0f) + 1e-5f);
            float h0 = fmaf(a0[r] * rs, gam0, bet0);
            float h1 = fmaf(a1[r] * rs, gam1, bet1);
            h0 = fmaxf(h0, 0.0f); h1 = fmaxf(h1, 0.0f);
            float t0 = tanh_fast(h0), t1 = tanh_fast(h1);
            float t02 = t0 * t0, t12 = t1 * t1;
            float zp = fmaf(e2a.x, t0, fmaf(e2a.y, t02,
                        fmaf(e2a.z, t02 * t0, e2a.w * (t02 * t02))));
            zp += fmaf(e2b.x, t1, fmaf(e2b.y, t12,
                    fmaf(e2b.z, t12 * t1, e2b.w * (t12 * t12))));
            z[r] = zp;
        }
        #pragma unroll
        for (int m = 1; m <= 8; m <<= 1) {
            #pragma unroll
            for (int r = 0; r < 4; ++r) z[r] += __shfl_xor(z[r], m, 64);
        }
        if (lr == 0) {
            #pragma unroll
            for (int r = 0; r < 4; ++r) {
                float attn = __builtin_amdgcn_rcpf(1.0f + __expf(-(z[r] + zb)));
                s_scale[wid * 64 + t * 16 + g * 4 + r] = fmaf(alpha, attn, 1.0f);
            }
        }
    }
    __syncthreads();

    // ---- coalesced gate sweep: out = PRV * (1 + alpha*attn) ----
    const size_t base = (size_t)blockIdx.x * 256 * (C_DIM / 4);
    const float4* prv4 = reinterpret_cast<const float4*>(PRV) + base;
    float4* out4 = reinterpret_cast<float4*>(out) + base;
    #pragma unroll 4
    for (int it = 0; it < C_DIM / 4; ++it) {
        int idx = it * 256 + tid;
        float sc = s_scale[idx >> 5];   // 32 float4 per row
        float4 v = prv4[idx];
        v.x *= sc; v.y *= sc; v.z *= sc; v.w *= sc;
        out4[idx] = v;
    }
}

extern "C" void kernel_launch(void* const* d_in, const int* in_sizes, int n_in,
                              void* d_out, int out_size, void* d_ws, size_t ws_size,
                              hipStream_t stream) {
    const float* PRV    = (const float*)d_in[0];
    const float* PR     = (const float*)d_in[1];
    const float* c1     = (const float*)d_in[2];
    const float* gamma  = (const float*)d_in[3];
    const float* beta   = (const float*)d_in[4];
    const float* c2     = (const float*)d_in[5];
    const float* alphap = (const float*)d_in[6];
    float* out = (float*)d_out;

    unsigned short* Bpack = (unsigned short*)d_ws;            // 32 KB bf16 frags
    float* wsf   = (float*)((char*)d_ws + 32768);
    float* bias1 = wsf;          // 32
    float* E2    = wsf + 32;     // 128 (32 x float4)
    float* bias2 = wsf + 160;    // 1

    const int N = in_sizes[0] / C_DIM;

    hipLaunchKernelGGL(prep_kernel, dim3(64), dim3(256), 0, stream,
                       c1, c2, Bpack, bias1, E2, bias2);
    hipLaunchKernelGGL(fused_kernel, dim3(N / 256), dim3(256), 0, stream,
                       PRV, PR, Bpack, bias1, E2, bias2, gamma, beta, alphap, out);
}

// Round 5
// 88.899 us; speedup vs baseline: 2.6562x; 1.0255x over previous
//
#include <hip/hip_runtime.h>
#include <hip/hip_bf16.h>

#define C_DIM 128
#define H_DIM 32

typedef __attribute__((ext_vector_type(8))) short bf16x8;
typedef __attribute__((ext_vector_type(4))) float f32x4;

// fast tanh: tanh(x) = 1 - 2/(e^{2x}+1). Handles +-inf correctly.
__device__ __forceinline__ float tanh_fast(float x) {
    float e = __expf(2.0f * x);
    return 1.0f - 2.0f * __builtin_amdgcn_rcpf(e + 1.0f);
}

// f32 -> bf16 RNE via library cast (compiler emits v_cvt_pk_bf16_f32 pairs)
__device__ __forceinline__ short f2bf(float f) {
    return __builtin_bit_cast(short, __float2bfloat16(f));
}

// Chebyshev -> monomial: p(t) = e0 + e1 t + e2 t^2 + e3 t^3 + e4 t^4
//   e0 = c0 - c2 + c4; e1 = c1 - 3c3; e2 = 2c2 - 8c4; e3 = 4c3; e4 = 8c4
// e0 folded into bias1 (summed over channels).
//
// Layer-1 coeffs packed directly in MFMA B-fragment order (bf16):
//   Bpack[kc][oh][lane][j]:
//     col     = oh*16 + (lane&15)
//     channel = (kc>>1)*16 + 4*(lane>>4) + 2*(kc&1) + (j>>2)
//     power   = (j&3) -> e_{p+1}
// The A-fragment builder uses the IDENTICAL (lane,j)->(channel,power) map,
// so any hardware k-permutation cancels (A/B fragment layouts are symmetric).
// This map makes each lane's per-kc2 A-input one aligned float4 of PR.
__global__ void prep_kernel(const float* __restrict__ c1, const float* __restrict__ c2,
                            unsigned short* __restrict__ Bpack, float* __restrict__ bias1,
                            float* __restrict__ E2, float* __restrict__ bias2) {
    const int tid = threadIdx.x;
    const int idx = blockIdx.x * 256 + tid;   // grid 64*256 = 16384 = one per element
    {
        int kc = idx >> 10;
        int oh = (idx >> 9) & 1;
        int l  = (idx >> 3) & 63;
        int j  = idx & 7;
        int g  = l >> 4;
        int kc2 = kc >> 1, kh = kc & 1;
        int c   = kc2 * 16 + 4 * g + 2 * kh + (j >> 2);
        int col = oh * 16 + (l & 15);
        int p   = j & 3;
        const float* cc = c1 + (c * H_DIM + col) * 5;
        float v = (p == 0) ? cc[1] - 3.0f * cc[3]
                : (p == 1) ? 2.0f * cc[2] - 8.0f * cc[4]
                : (p == 2) ? 4.0f * cc[3]
                           : 8.0f * cc[4];
        Bpack[idx] = (unsigned short)f2bf(v);
    }
    if (blockIdx.x == 0) {
        __shared__ float part[256];
        // bias1[o] = sum_i e0[i,o]; 8-way split over channel chunks
        const int o = tid & 31, ch = tid >> 5;
        float b = 0.0f;
        for (int i = ch * 16; i < ch * 16 + 16; ++i) {
            const float* cc = c1 + (i * H_DIM + o) * 5;
            b += cc[0] - cc[2] + cc[4];
        }
        part[tid] = b;
        __syncthreads();
        if (tid < 32) {
            float s = 0.0f;
            #pragma unroll
            for (int k = 0; k < 8; ++k) s += part[k * 32 + tid];
            bias1[tid] = s;
            const float* cc = c2 + tid * 5;
            float4 e;
            e.x = cc[1] - 3.0f * cc[3];
            e.y = 2.0f * cc[2] - 8.0f * cc[4];
            e.z = 4.0f * cc[3];
            e.w = 8.0f * cc[4];
            reinterpret_cast<float4*>(E2)[tid] = e;
        }
        __syncthreads();
        if (tid < 32) part[tid] = c2[tid * 5] - c2[tid * 5 + 2] + c2[tid * 5 + 4];
        __syncthreads();
        if (tid == 0) {
            float b2 = 0.0f;
            for (int h = 0; h < 32; ++h) b2 += part[h];
            bias2[0] = b2;
        }
    }
}

// 512-thread blocks (8 waves), 32 rows/wave, 256 rows/block.
// LDS 33 KB -> 4 blocks/CU = 32 waves/CU (100% occupancy);
// __launch_bounds__(512,8) caps VGPR at 64 to allow 8 waves/SIMD.
__global__ __launch_bounds__(512, 8) void fused_kernel(
        const float* __restrict__ PRV, const float* __restrict__ PR,
        const unsigned short* __restrict__ Bpack, const float* __restrict__ bias1,
        const float* __restrict__ E2, const float* __restrict__ bias2,
        const float* __restrict__ gamma, const float* __restrict__ beta,
        const float* __restrict__ alphap, float* __restrict__ out) {
    __shared__ short sB[16 * 2 * 64 * 8];   // 32 KB: B-frags in lane order
    __shared__ float s_scale[256];

    const int tid  = threadIdx.x;
    const int wid  = tid >> 6;
    const int lane = tid & 63;
    const int g    = lane >> 4;
    const int lr   = lane & 15;

    // per-lane PR pointers (float4 of 4 consecutive channels per kc2)
    const float4* pr4 = reinterpret_cast<const float4*>(PR);
    const size_t rbase = (size_t)blockIdx.x * 256 + wid * 32 + lr;
    const float4* q0 = pr4 + (rbase +  0) * (C_DIM / 4) + g;
    const float4* q1 = pr4 + (rbase + 16) * (C_DIM / 4) + g;

    // issue first PR loads before B-staging so HBM latency overlaps staging
    float4 xc0 = q0[0], xc1 = q1[0];

    // stage B fragments into LDS, coalesced (32 KB / 512 thr = 4 float4 each)
    {
        const float4* src = reinterpret_cast<const float4*>(Bpack);
        float4* dst = reinterpret_cast<float4*>(sB);
        #pragma unroll
        for (int j = 0; j < 4; ++j) dst[j * 512 + tid] = src[j * 512 + tid];
    }
    __syncthreads();

    f32x4 acc[2][2];
    {
        float b0 = bias1[lr], b1 = bias1[16 + lr];
        #pragma unroll
        for (int t = 0; t < 2; ++t) {
            acc[t][0] = (f32x4){b0, b0, b0, b0};
            acc[t][1] = (f32x4){b1, b1, b1, b1};
        }
    }

    const bf16x8* sB8 = reinterpret_cast<const bf16x8*>(sB);

    // K-loop: 8 chunks of K=64 (16 channels x 4 powers), depth-2 pipelined
    #pragma unroll 1
    for (int kc2 = 0; kc2 < 8; ++kc2) {
        const int nk = ((kc2 + 1) & 7) * 4;   // wrap: L1-resident re-read, harmless
        float4 xn0 = q0[nk], xn1 = q1[nk];
        bf16x8 be0 = sB8[(kc2 * 4 + 0) * 64 + lane];
        bf16x8 be1 = sB8[(kc2 * 4 + 1) * 64 + lane];
        bf16x8 bo0 = sB8[(kc2 * 4 + 2) * 64 + lane];
        bf16x8 bo1 = sB8[(kc2 * 4 + 3) * 64 + lane];
        #define DO_TILE(XC, T) { \
            float t0 = tanh_fast(XC.x), t1 = tanh_fast(XC.y); \
            float t2 = tanh_fast(XC.z), t3 = tanh_fast(XC.w); \
            float s0 = t0 * t0, s1 = t1 * t1, s2 = t2 * t2, s3 = t3 * t3; \
            bf16x8 ae, ao; \
            ae[0] = f2bf(t0); ae[1] = f2bf(s0); ae[2] = f2bf(s0 * t0); ae[3] = f2bf(s0 * s0); \
            ae[4] = f2bf(t1); ae[5] = f2bf(s1); ae[6] = f2bf(s1 * t1); ae[7] = f2bf(s1 * s1); \
            ao[0] = f2bf(t2); ao[1] = f2bf(s2); ao[2] = f2bf(s2 * t2); ao[3] = f2bf(s2 * s2); \
            ao[4] = f2bf(t3); ao[5] = f2bf(s3); ao[6] = f2bf(s3 * t3); ao[7] = f2bf(s3 * s3); \
            acc[T][0] = __builtin_amdgcn_mfma_f32_16x16x32_bf16(ae, be0, acc[T][0], 0, 0, 0); \
            acc[T][1] = __builtin_amdgcn_mfma_f32_16x16x32_bf16(ae, be1, acc[T][1], 0, 0, 0); \
            acc[T][0] = __builtin_amdgcn_mfma_f32_16x16x32_bf16(ao, bo0, acc[T][0], 0, 0, 0); \
            acc[T][1] = __builtin_amdgcn_mfma_f32_16x16x32_bf16(ao, bo1, acc[T][1], 0, 0, 0); }
        DO_TILE(xc0, 0)
        DO_TILE(xc1, 1)
        #undef DO_TILE
        xc0 = xn0; xc1 = xn1;
    }

    // ---- LayerNorm + ReLU + layer-2 ChebyKAN + sigmoid, per M-tile ----
    // C layout: col = oh*16 + lr, row = g*4 + reg  (verified m89/m91)
    const float gam0 = gamma[lr], gam1 = gamma[16 + lr];
    const float bet0 = beta[lr],  bet1 = beta[16 + lr];
    const float4 e2a = reinterpret_cast<const float4*>(E2)[lr];
    const float4 e2b = reinterpret_cast<const float4*>(E2)[16 + lr];
    const float zb = bias2[0];
    const float alpha = alphap[0];

    #pragma unroll
    for (int t = 0; t < 2; ++t) {
        f32x4 a0 = acc[t][0], a1 = acc[t][1];
        float s[4], vs[4], z[4];
        #pragma unroll
        for (int r = 0; r < 4; ++r) s[r] = a0[r] + a1[r];
        #pragma unroll
        for (int m = 1; m <= 8; m <<= 1) {
            #pragma unroll
            for (int r = 0; r < 4; ++r) s[r] += __shfl_xor(s[r], m, 64);
        }
        #pragma unroll
        for (int r = 0; r < 4; ++r) {
            float mu = s[r] * (1.0f / 32.0f);
            float d0 = a0[r] - mu, d1 = a1[r] - mu;
            a0[r] = d0; a1[r] = d1;
            vs[r] = d0 * d0 + d1 * d1;
        }
        #pragma unroll
        for (int m = 1; m <= 8; m <<= 1) {
            #pragma unroll
            for (int r = 0; r < 4; ++r) vs[r] += __shfl_xor(vs[r], m, 64);
        }
        #pragma unroll
        for (int r = 0; r < 4; ++r) {
            float rs = rsqrtf(vs[r] * (1.0f / 32.0f) + 1e-5f);
            float h0 = fmaf(a0[r] * rs, gam0, bet0);
            float h1 = fmaf(a1[r] * rs, gam1, bet1);
            h0 = fmaxf(h0, 0.0f); h1 = fmaxf(h1, 0.0f);
            float t0 = tanh_fast(h0), t1 = tanh_fast(h1);
            float t02 = t0 * t0, t12 = t1 * t1;
            float zp = fmaf(e2a.x, t0, fmaf(e2a.y, t02,
                        fmaf(e2a.z, t02 * t0, e2a.w * (t02 * t02))));
            zp += fmaf(e2b.x, t1, fmaf(e2b.y, t12,
                    fmaf(e2b.z, t12 * t1, e2b.w * (t12 * t12))));
            z[r] = zp;
        }
        #pragma unroll
        for (int m = 1; m <= 8; m <<= 1) {
            #pragma unroll
            for (int r = 0; r < 4; ++r) z[r] += __shfl_xor(z[r], m, 64);
        }
        if (lr == 0) {
            #pragma unroll
            for (int r = 0; r < 4; ++r) {
                float attn = __builtin_amdgcn_rcpf(1.0f + __expf(-(z[r] + zb)));
                s_scale[wid * 32 + t * 16 + g * 4 + r] = fmaf(alpha, attn, 1.0f);
            }
        }
    }
    __syncthreads();

    // ---- coalesced gate sweep: out = PRV * (1 + alpha*attn) ----
    const size_t base = (size_t)blockIdx.x * 256 * (C_DIM / 4);
    const float4* prv4 = reinterpret_cast<const float4*>(PRV) + base;
    float4* out4 = reinterpret_cast<float4*>(out) + base;
    #pragma unroll 4
    for (int it = 0; it < 16; ++it) {
        int idx = it * 512 + tid;
        float sc = s_scale[idx >> 5];   // 32 float4 per row
        float4 v = prv4[idx];
        v.x *= sc; v.y *= sc; v.z *= sc; v.w *= sc;
        out4[idx] = v;
    }
}

extern "C" void kernel_launch(void* const* d_in, const int* in_sizes, int n_in,
                              void* d_out, int out_size, void* d_ws, size_t ws_size,
                              hipStream_t stream) {
    const float* PRV    = (const float*)d_in[0];
    const float* PR     = (const float*)d_in[1];
    const float* c1     = (const float*)d_in[2];
    const float* gamma  = (const float*)d_in[3];
    const float* beta   = (const float*)d_in[4];
    const float* c2     = (const float*)d_in[5];
    const float* alphap = (const float*)d_in[6];
    float* out = (float*)d_out;

    unsigned short* Bpack = (unsigned short*)d_ws;            // 32 KB bf16 frags
    float* wsf   = (float*)((char*)d_ws + 32768);
    float* bias1 = wsf;          // 32
    float* E2    = wsf + 32;     // 128 (32 x float4)
    float* bias2 = wsf + 160;    // 1

    const int N = in_sizes[0] / C_DIM;

    hipLaunchKernelGGL(prep_kernel, dim3(64), dim3(256), 0, stream,
                       c1, c2, Bpack, bias1, E2, bias2);
    hipLaunchKernelGGL(fused_kernel, dim3(N / 256), dim3(512), 0, stream,
                       PRV, PR, Bpack, bias1, E2, bias2, gamma, beta, alphap, out);
}

// Round 6
// 87.421 us; speedup vs baseline: 2.7011x; 1.0169x over previous
//
#include <hip/hip_runtime.h>
#include <hip/hip_bf16.h>

#define C_DIM 128
#define H_DIM 32

typedef __attribute__((ext_vector_type(8))) short bf16x8;
typedef __attribute__((ext_vector_type(4))) float f32x4;

// fast tanh: tanh(x) = 1 - 2/(e^{2x}+1). Handles +-inf correctly.
__device__ __forceinline__ float tanh_fast(float x) {
    float e = __expf(2.0f * x);
    return 1.0f - 2.0f * __builtin_amdgcn_rcpf(e + 1.0f);
}

// f32 -> bf16 RNE via library cast (compiler emits v_cvt_pk_bf16_f32 pairs)
__device__ __forceinline__ short f2bf(float f) {
    return __builtin_bit_cast(short, __float2bfloat16(f));
}

// Chebyshev -> monomial: p(t) = e0 + e1 t + e2 t^2 + e3 t^3 + e4 t^4
//   e0 = c0 - c2 + c4; e1 = c1 - 3c3; e2 = 2c2 - 8c4; e3 = 4c3; e4 = 8c4
// e0 folded into bias1 (summed over channels).
//
// Layer-1 coeffs packed directly in MFMA B-fragment order (bf16):
//   Bpack[kc][oh][lane][j]:
//     col     = oh*16 + (lane&15)
//     channel = (kc>>1)*16 + 4*(lane>>4) + 2*(kc&1) + (j>>2)
//     power   = (j&3) -> e_{p+1}
// The A-fragment builder uses the IDENTICAL (lane,j)->(channel,power) map,
// so any hardware k-permutation cancels (A/B fragment layouts are symmetric).
// This map makes each lane's per-kc2 A-input one aligned float4 of PR.
__global__ void prep_kernel(const float* __restrict__ c1, const float* __restrict__ c2,
                            unsigned short* __restrict__ Bpack, float* __restrict__ bias1,
                            float* __restrict__ E2, float* __restrict__ bias2) {
    const int tid = threadIdx.x;
    const int idx = blockIdx.x * 256 + tid;   // grid 64*256 = 16384 = one per element
    {
        int kc = idx >> 10;
        int oh = (idx >> 9) & 1;
        int l  = (idx >> 3) & 63;
        int j  = idx & 7;
        int g  = l >> 4;
        int kc2 = kc >> 1, kh = kc & 1;
        int c   = kc2 * 16 + 4 * g + 2 * kh + (j >> 2);
        int col = oh * 16 + (l & 15);
        int p   = j & 3;
        const float* cc = c1 + (c * H_DIM + col) * 5;
        float v = (p == 0) ? cc[1] - 3.0f * cc[3]
                : (p == 1) ? 2.0f * cc[2] - 8.0f * cc[4]
                : (p == 2) ? 4.0f * cc[3]
                           : 8.0f * cc[4];
        Bpack[idx] = (unsigned short)f2bf(v);
    }
    if (blockIdx.x == 0) {
        __shared__ float part[256];
        // bias1[o] = sum_i e0[i,o]; 8-way split over channel chunks
        const int o = tid & 31, ch = tid >> 5;
        float b = 0.0f;
        for (int i = ch * 16; i < ch * 16 + 16; ++i) {
            const float* cc = c1 + (i * H_DIM + o) * 5;
            b += cc[0] - cc[2] + cc[4];
        }
        part[tid] = b;
        __syncthreads();
        if (tid < 32) {
            float s = 0.0f;
            #pragma unroll
            for (int k = 0; k < 8; ++k) s += part[k * 32 + tid];
            bias1[tid] = s;
            const float* cc = c2 + tid * 5;
            float4 e;
            e.x = cc[1] - 3.0f * cc[3];
            e.y = 2.0f * cc[2] - 8.0f * cc[4];
            e.z = 4.0f * cc[3];
            e.w = 8.0f * cc[4];
            reinterpret_cast<float4*>(E2)[tid] = e;
        }
        __syncthreads();
        if (tid < 32) part[tid] = c2[tid * 5] - c2[tid * 5 + 2] + c2[tid * 5 + 4];
        __syncthreads();
        if (tid == 0) {
            float b2 = 0.0f;
            for (int h = 0; h < 32; ++h) b2 += part[h];
            bias2[0] = b2;
        }
    }
}

// 512-thread blocks (8 waves), 32 rows/wave, 256 rows/block.
// __launch_bounds__(512,4): VGPR cap 128 so the FULL per-wave PR working set
// (16 float4 = 64 VGPR) can be issued as one burst at kernel entry -> the
// K-loop has zero global loads and the GEMM phase turns BW-bound instead of
// latency-bound (R5 lesson: VGPR=32 serialized the pipeline; occupancy was
// NOT the limiter - 35% vs 68% gave identical profiled duration).
__global__ __launch_bounds__(512, 4) void fused_kernel(
        const float* __restrict__ PRV, const float* __restrict__ PR,
        const unsigned short* __restrict__ Bpack, const float* __restrict__ bias1,
        const float* __restrict__ E2, const float* __restrict__ bias2,
        const float* __restrict__ gamma, const float* __restrict__ beta,
        const float* __restrict__ alphap, float* __restrict__ out) {
    __shared__ short sB[16 * 2 * 64 * 8];   // 32 KB: B-frags in lane order
    __shared__ float s_scale[256];

    const int tid  = threadIdx.x;
    const int wid  = tid >> 6;
    const int lane = tid & 63;
    const int g    = lane >> 4;
    const int lr   = lane & 15;

    // per-lane PR pointers (float4 of 4 consecutive channels per kc2)
    const float4* pr4 = reinterpret_cast<const float4*>(PR);
    const size_t rbase = (size_t)blockIdx.x * 256 + wid * 32 + lr;
    const float4* q0 = pr4 + (rbase +  0) * (C_DIM / 4) + g;
    const float4* q1 = pr4 + (rbase + 16) * (C_DIM / 4) + g;

    // burst-issue the ENTIRE per-wave PR working set (16 KB/wave in flight)
    float4 xa[8], xb[8];
    #pragma unroll
    for (int k = 0; k < 8; ++k) { xa[k] = q0[k * 4]; xb[k] = q1[k * 4]; }

    // stage B fragments into LDS, coalesced (32 KB / 512 thr = 4 float4 each)
    {
        const float4* src = reinterpret_cast<const float4*>(Bpack);
        float4* dst = reinterpret_cast<float4*>(sB);
        #pragma unroll
        for (int j = 0; j < 4; ++j) dst[j * 512 + tid] = src[j * 512 + tid];
    }
    __syncthreads();

    f32x4 acc[2][2];
    {
        float b0 = bias1[lr], b1 = bias1[16 + lr];
        #pragma unroll
        for (int t = 0; t < 2; ++t) {
            acc[t][0] = (f32x4){b0, b0, b0, b0};
            acc[t][1] = (f32x4){b1, b1, b1, b1};
        }
    }

    const bf16x8* sB8 = reinterpret_cast<const bf16x8*>(sB);

    // K-loop: 8 chunks of K=64, fully unrolled, no global loads inside
    #pragma unroll
    for (int kc2 = 0; kc2 < 8; ++kc2) {
        bf16x8 be0 = sB8[(kc2 * 4 + 0) * 64 + lane];
        bf16x8 be1 = sB8[(kc2 * 4 + 1) * 64 + lane];
        bf16x8 bo0 = sB8[(kc2 * 4 + 2) * 64 + lane];
        bf16x8 bo1 = sB8[(kc2 * 4 + 3) * 64 + lane];
        #define DO_TILE(XC, T) { \
            float t0 = tanh_fast(XC.x), t1 = tanh_fast(XC.y); \
            float t2 = tanh_fast(XC.z), t3 = tanh_fast(XC.w); \
            float s0 = t0 * t0, s1 = t1 * t1, s2 = t2 * t2, s3 = t3 * t3; \
            bf16x8 ae, ao; \
            ae[0] = f2bf(t0); ae[1] = f2bf(s0); ae[2] = f2bf(s0 * t0); ae[3] = f2bf(s0 * s0); \
            ae[4] = f2bf(t1); ae[5] = f2bf(s1); ae[6] = f2bf(s1 * t1); ae[7] = f2bf(s1 * s1); \
            ao[0] = f2bf(t2); ao[1] = f2bf(s2); ao[2] = f2bf(s2 * t2); ao[3] = f2bf(s2 * s2); \
            ao[4] = f2bf(t3); ao[5] = f2bf(s3); ao[6] = f2bf(s3 * t3); ao[7] = f2bf(s3 * s3); \
            acc[T][0] = __builtin_amdgcn_mfma_f32_16x16x32_bf16(ae, be0, acc[T][0], 0, 0, 0); \
            acc[T][1] = __builtin_amdgcn_mfma_f32_16x16x32_bf16(ae, be1, acc[T][1], 0, 0, 0); \
            acc[T][0] = __builtin_amdgcn_mfma_f32_16x16x32_bf16(ao, bo0, acc[T][0], 0, 0, 0); \
            acc[T][1] = __builtin_amdgcn_mfma_f32_16x16x32_bf16(ao, bo1, acc[T][1], 0, 0, 0); }
        DO_TILE(xa[kc2], 0)
        DO_TILE(xb[kc2], 1)
        #undef DO_TILE
    }

    // ---- LayerNorm + ReLU + layer-2 ChebyKAN + sigmoid, per M-tile ----
    // C layout: col = oh*16 + lr, row = g*4 + reg  (verified m89/m91)
    const float gam0 = gamma[lr], gam1 = gamma[16 + lr];
    const float bet0 = beta[lr],  bet1 = beta[16 + lr];
    const float4 e2a = reinterpret_cast<const float4*>(E2)[lr];
    const float4 e2b = reinterpret_cast<const float4*>(E2)[16 + lr];
    const float zb = bias2[0];
    const float alpha = alphap[0];

    #pragma unroll
    for (int t = 0; t < 2; ++t) {
        f32x4 a0 = acc[t][0], a1 = acc[t][1];
        float s[4], vs[4], z[4];
        #pragma unroll
        for (int r = 0; r < 4; ++r) s[r] = a0[r] + a1[r];
        #pragma unroll
        for (int m = 1; m <= 8; m <<= 1) {
            #pragma unroll
            for (int r = 0; r < 4; ++r) s[r] += __shfl_xor(s[r], m, 64);
        }
        #pragma unroll
        for (int r = 0; r < 4; ++r) {
            float mu = s[r] * (1.0f / 32.0f);
            float d0 = a0[r] - mu, d1 = a1[r] - mu;
            a0[r] = d0; a1[r] = d1;
            vs[r] = d0 * d0 + d1 * d1;
        }
        #pragma unroll
        for (int m = 1; m <= 8; m <<= 1) {
            #pragma unroll
            for (int r = 0; r < 4; ++r) vs[r] += __shfl_xor(vs[r], m, 64);
        }
        #pragma unroll
        for (int r = 0; r < 4; ++r) {
            float rs = rsqrtf(vs[r] * (1.0f / 32.0f) + 1e-5f);
            float h0 = fmaf(a0[r] * rs, gam0, bet0);
            float h1 = fmaf(a1[r] * rs, gam1, bet1);
            h0 = fmaxf(h0, 0.0f); h1 = fmaxf(h1, 0.0f);
            float t0 = tanh_fast(h0), t1 = tanh_fast(h1);
            float t02 = t0 * t0, t12 = t1 * t1;
            float zp = fmaf(e2a.x, t0, fmaf(e2a.y, t02,
                        fmaf(e2a.z, t02 * t0, e2a.w * (t02 * t02))));
            zp += fmaf(e2b.x, t1, fmaf(e2b.y, t12,
                    fmaf(e2b.z, t12 * t1, e2b.w * (t12 * t12))));
            z[r] = zp;
        }
        #pragma unroll
        for (int m = 1; m <= 8; m <<= 1) {
            #pragma unroll
            for (int r = 0; r < 4; ++r) z[r] += __shfl_xor(z[r], m, 64);
        }
        if (lr == 0) {
            #pragma unroll
            for (int r = 0; r < 4; ++r) {
                float attn = __builtin_amdgcn_rcpf(1.0f + __expf(-(z[r] + zb)));
                s_scale[wid * 32 + t * 16 + g * 4 + r] = fmaf(alpha, attn, 1.0f);
            }
        }
    }
    __syncthreads();

    // ---- coalesced gate sweep: out = PRV * (1 + alpha*attn) ----
    const size_t base = (size_t)blockIdx.x * 256 * (C_DIM / 4);
    const float4* prv4 = reinterpret_cast<const float4*>(PRV) + base;
    float4* out4 = reinterpret_cast<float4*>(out) + base;
    #pragma unroll 4
    for (int it = 0; it < 16; ++it) {
        int idx = it * 512 + tid;
        float sc = s_scale[idx >> 5];   // 32 float4 per row
        float4 v = prv4[idx];
        v.x *= sc; v.y *= sc; v.z *= sc; v.w *= sc;
        out4[idx] = v;
    }
}

extern "C" void kernel_launch(void* const* d_in, const int* in_sizes, int n_in,
                              void* d_out, int out_size, void* d_ws, size_t ws_size,
                              hipStream_t stream) {
    const float* PRV    = (const float*)d_in[0];
    const float* PR     = (const float*)d_in[1];
    const float* c1     = (const float*)d_in[2];
    const float* gamma  = (const float*)d_in[3];
    const float* beta   = (const float*)d_in[4];
    const float* c2     = (const float*)d_in[5];
    const float* alphap = (const float*)d_in[6];
    float* out = (float*)d_out;

    unsigned short* Bpack = (unsigned short*)d_ws;            // 32 KB bf16 frags
    float* wsf   = (float*)((char*)d_ws + 32768);
    float* bias1 = wsf;          // 32
    float* E2    = wsf + 32;     // 128 (32 x float4)
    float* bias2 = wsf + 160;    // 1

    const int N = in_sizes[0] / C_DIM;

    hipLaunchKernelGGL(prep_kernel, dim3(64), dim3(256), 0, stream,
                       c1, c2, Bpack, bias1, E2, bias2);
    hipLaunchKernelGGL(fused_kernel, dim3(N / 256), dim3(512), 0, stream,
                       PRV, PR, Bpack, bias1, E2, bias2, gamma, beta, alphap, out);
}

// Round 7
// 87.114 us; speedup vs baseline: 2.7106x; 1.0035x over previous
//
#include <hip/hip_runtime.h>
#include <hip/hip_bf16.h>

#define C_DIM 128
#define H_DIM 32

typedef __attribute__((ext_vector_type(8))) short bf16x8;
typedef __attribute__((ext_vector_type(4))) float f32x4;

// fast tanh: tanh(x) = 1 - 2/(e^{2x}+1). Handles +-inf correctly.
__device__ __forceinline__ float tanh_fast(float x) {
    float e = __expf(2.0f * x);
    return 1.0f - 2.0f * __builtin_amdgcn_rcpf(e + 1.0f);
}

// f32 -> bf16 RNE via library cast (compiler emits v_cvt_pk_bf16_f32 pairs)
__device__ __forceinline__ short f2bf(float f) {
    return __builtin_bit_cast(short, __float2bfloat16(f));
}

// Chebyshev -> monomial: p(t) = e0 + e1 t + e2 t^2 + e3 t^3 + e4 t^4
//   e0 = c0 - c2 + c4; e1 = c1 - 3c3; e2 = 2c2 - 8c4; e3 = 4c3; e4 = 8c4
// e0 folded into bias1 (summed over channels).
//
// Layer-1 coeffs packed directly in MFMA B-fragment order (bf16):
//   Bpack[kc][oh][lane][j]:
//     col     = oh*16 + (lane&15)
//     channel = (kc>>1)*16 + 4*(lane>>4) + 2*(kc&1) + (j>>2)
//     power   = (j&3) -> e_{p+1}
// A-fragment builder uses the IDENTICAL map, so any hw k-permutation cancels.
__global__ void prep_kernel(const float* __restrict__ c1, const float* __restrict__ c2,
                            unsigned short* __restrict__ Bpack, float* __restrict__ bias1,
                            float* __restrict__ E2, float* __restrict__ bias2) {
    const int tid = threadIdx.x;
    const int idx = blockIdx.x * 256 + tid;   // grid 64*256 = 16384 = one per element
    {
        int kc = idx >> 10;
        int oh = (idx >> 9) & 1;
        int l  = (idx >> 3) & 63;
        int j  = idx & 7;
        int g  = l >> 4;
        int kc2 = kc >> 1, kh = kc & 1;
        int c   = kc2 * 16 + 4 * g + 2 * kh + (j >> 2);
        int col = oh * 16 + (l & 15);
        int p   = j & 3;
        const float* cc = c1 + (c * H_DIM + col) * 5;
        float v = (p == 0) ? cc[1] - 3.0f * cc[3]
                : (p == 1) ? 2.0f * cc[2] - 8.0f * cc[4]
                : (p == 2) ? 4.0f * cc[3]
                           : 8.0f * cc[4];
        Bpack[idx] = (unsigned short)f2bf(v);
    }
    if (blockIdx.x == 0) {
        __shared__ float part[256];
        const int o = tid & 31, ch = tid >> 5;
        float b = 0.0f;
        for (int i = ch * 16; i < ch * 16 + 16; ++i) {
            const float* cc = c1 + (i * H_DIM + o) * 5;
            b += cc[0] - cc[2] + cc[4];
        }
        part[tid] = b;
        __syncthreads();
        if (tid < 32) {
            float s = 0.0f;
            #pragma unroll
            for (int k = 0; k < 8; ++k) s += part[k * 32 + tid];
            bias1[tid] = s;
            const float* cc = c2 + tid * 5;
            float4 e;
            e.x = cc[1] - 3.0f * cc[3];
            e.y = 2.0f * cc[2] - 8.0f * cc[4];
            e.z = 4.0f * cc[3];
            e.w = 8.0f * cc[4];
            reinterpret_cast<float4*>(E2)[tid] = e;
        }
        __syncthreads();
        if (tid < 32) part[tid] = c2[tid * 5] - c2[tid * 5 + 2] + c2[tid * 5 + 4];
        __syncthreads();
        if (tid == 0) {
            float b2 = 0.0f;
            for (int h = 0; h < 32; ++h) b2 += part[h];
            bias2[0] = b2;
        }
    }
}

// R7 structure: per-wave end-to-end (GEMM -> epilogue -> own-rows sweep),
// no second __syncthreads. PRV prefetch is pinned with inline-asm
// global_load_dwordx4 issued right after the K-loop (compiler is vmcnt-blind
// to them -> cannot rematerialize/sink, the R6 failure). Consumes use
// value-tied s_waitcnt vmcnt(15-it): vmcnt retires in issue order (m135),
// and at the first asm the compiler's vmem counter is 0 (all K-loop PR
// loads were consumed, hence waited). Decreasing counts stay correct
// whether or not stores are interleaved (over-wait only).
__global__ __launch_bounds__(512, 4) void fused_kernel(
        const float* __restrict__ PRV, const float* __restrict__ PR,
        const unsigned short* __restrict__ Bpack, const float* __restrict__ bias1,
        const float* __restrict__ E2, const float* __restrict__ bias2,
        const float* __restrict__ gamma, const float* __restrict__ beta,
        const float* __restrict__ alphap, float* __restrict__ out) {
    __shared__ short sB[16 * 2 * 64 * 8];   // 32 KB: B-frags in lane order
    __shared__ float s_scale[256];

    const int tid  = threadIdx.x;
    const int wid  = tid >> 6;
    const int lane = tid & 63;
    const int g    = lane >> 4;
    const int lr   = lane & 15;
    const int hi   = lane >> 5;

    // per-lane PR pointers (float4 of 4 consecutive channels per kc2)
    const float4* pr4 = reinterpret_cast<const float4*>(PR);
    const size_t rbase = (size_t)blockIdx.x * 256 + wid * 32 + lr;
    const float4* q0 = pr4 + (rbase +  0) * (C_DIM / 4) + g;
    const float4* q1 = pr4 + (rbase + 16) * (C_DIM / 4) + g;

    // stage B fragments into LDS, coalesced (32 KB / 512 thr = 4 float4 each)
    {
        const float4* src = reinterpret_cast<const float4*>(Bpack);
        float4* dst = reinterpret_cast<float4*>(sB);
        #pragma unroll
        for (int j = 0; j < 4; ++j) dst[j * 512 + tid] = src[j * 512 + tid];
    }
    __syncthreads();

    // epilogue constants hoisted BEFORE the K-loop so the epilogue contains
    // no compiler vector-loads (they would drain our pinned prefetch queue)
    const float gam0 = gamma[lr], gam1 = gamma[16 + lr];
    const float bet0 = beta[lr],  bet1 = beta[16 + lr];
    const float4 e2a = reinterpret_cast<const float4*>(E2)[lr];
    const float4 e2b = reinterpret_cast<const float4*>(E2)[16 + lr];
    const float zb = bias2[0];
    const float alpha = alphap[0];

    f32x4 acc[2][2];
    {
        float b0 = bias1[lr], b1 = bias1[16 + lr];
        #pragma unroll
        for (int t = 0; t < 2; ++t) {
            acc[t][0] = (f32x4){b0, b0, b0, b0};
            acc[t][1] = (f32x4){b1, b1, b1, b1};
        }
    }

    const bf16x8* sB8 = reinterpret_cast<const bf16x8*>(sB);

    // K-loop: 8 chunks of K=64, fully unrolled
    #pragma unroll
    for (int kc2 = 0; kc2 < 8; ++kc2) {
        float4 x0 = q0[kc2 * 4];
        float4 x1 = q1[kc2 * 4];
        bf16x8 be0 = sB8[(kc2 * 4 + 0) * 64 + lane];
        bf16x8 be1 = sB8[(kc2 * 4 + 1) * 64 + lane];
        bf16x8 bo0 = sB8[(kc2 * 4 + 2) * 64 + lane];
        bf16x8 bo1 = sB8[(kc2 * 4 + 3) * 64 + lane];
        #define DO_TILE(XC, T) { \
            float t0 = tanh_fast(XC.x), t1 = tanh_fast(XC.y); \
            float t2 = tanh_fast(XC.z), t3 = tanh_fast(XC.w); \
            float s0 = t0 * t0, s1 = t1 * t1, s2 = t2 * t2, s3 = t3 * t3; \
            bf16x8 ae, ao; \
            ae[0] = f2bf(t0); ae[1] = f2bf(s0); ae[2] = f2bf(s0 * t0); ae[3] = f2bf(s0 * s0); \
            ae[4] = f2bf(t1); ae[5] = f2bf(s1); ae[6] = f2bf(s1 * t1); ae[7] = f2bf(s1 * s1); \
            ao[0] = f2bf(t2); ao[1] = f2bf(s2); ao[2] = f2bf(s2 * t2); ao[3] = f2bf(s2 * s2); \
            ao[4] = f2bf(t3); ao[5] = f2bf(s3); ao[6] = f2bf(s3 * t3); ao[7] = f2bf(s3 * s3); \
            acc[T][0] = __builtin_amdgcn_mfma_f32_16x16x32_bf16(ae, be0, acc[T][0], 0, 0, 0); \
            acc[T][1] = __builtin_amdgcn_mfma_f32_16x16x32_bf16(ae, be1, acc[T][1], 0, 0, 0); \
            acc[T][0] = __builtin_amdgcn_mfma_f32_16x16x32_bf16(ao, bo0, acc[T][0], 0, 0, 0); \
            acc[T][1] = __builtin_amdgcn_mfma_f32_16x16x32_bf16(ao, bo1, acc[T][1], 0, 0, 0); }
        DO_TILE(x0, 0)
        DO_TILE(x1, 1)
        #undef DO_TILE
    }

    // ---- pinned PRV prefetch: 16 x 1KB/wave, issued NOW, lands under the
    // epilogue's ~600 cycles of shuffle/LN/tanh work ----
    const f32x4* pvb = reinterpret_cast<const f32x4*>(PRV)
                       + (size_t)blockIdx.x * 8192 + wid * 1024 + lane;
    #define PVLD(IT) \
        f32x4 pv##IT; \
        asm volatile("global_load_dwordx4 %0, %1, off" \
                     : "=v"(pv##IT) : "v"(pvb + IT * 64));
    PVLD(0)  PVLD(1)  PVLD(2)  PVLD(3)
    PVLD(4)  PVLD(5)  PVLD(6)  PVLD(7)
    PVLD(8)  PVLD(9)  PVLD(10) PVLD(11)
    PVLD(12) PVLD(13) PVLD(14) PVLD(15)
    #undef PVLD

    // ---- LayerNorm + ReLU + layer-2 ChebyKAN + sigmoid, per M-tile ----
    // C layout: col = oh*16 + lr, row = g*4 + reg  (verified m89/m91)
    #pragma unroll
    for (int t = 0; t < 2; ++t) {
        f32x4 a0 = acc[t][0], a1 = acc[t][1];
        float s[4], vs[4], z[4];
        #pragma unroll
        for (int r = 0; r < 4; ++r) s[r] = a0[r] + a1[r];
        #pragma unroll
        for (int m = 1; m <= 8; m <<= 1) {
            #pragma unroll
            for (int r = 0; r < 4; ++r) s[r] += __shfl_xor(s[r], m, 64);
        }
        #pragma unroll
        for (int r = 0; r < 4; ++r) {
            float mu = s[r] * (1.0f / 32.0f);
            float d0 = a0[r] - mu, d1 = a1[r] - mu;
            a0[r] = d0; a1[r] = d1;
            vs[r] = d0 * d0 + d1 * d1;
        }
        #pragma unroll
        for (int m = 1; m <= 8; m <<= 1) {
            #pragma unroll
            for (int r = 0; r < 4; ++r) vs[r] += __shfl_xor(vs[r], m, 64);
        }
        #pragma unroll
        for (int r = 0; r < 4; ++r) {
            float rs = rsqrtf(vs[r] * (1.0f / 32.0f) + 1e-5f);
            float h0 = fmaf(a0[r] * rs, gam0, bet0);
            float h1 = fmaf(a1[r] * rs, gam1, bet1);
            h0 = fmaxf(h0, 0.0f); h1 = fmaxf(h1, 0.0f);
            float t0 = tanh_fast(h0), t1 = tanh_fast(h1);
            float t02 = t0 * t0, t12 = t1 * t1;
            float zp = fmaf(e2a.x, t0, fmaf(e2a.y, t02,
                        fmaf(e2a.z, t02 * t0, e2a.w * (t02 * t02))));
            zp += fmaf(e2b.x, t1, fmaf(e2b.y, t12,
                    fmaf(e2b.z, t12 * t1, e2b.w * (t12 * t12))));
            z[r] = zp;
        }
        #pragma unroll
        for (int m = 1; m <= 8; m <<= 1) {
            #pragma unroll
            for (int r = 0; r < 4; ++r) z[r] += __shfl_xor(z[r], m, 64);
        }
        if (lr == 0) {
            #pragma unroll
            for (int r = 0; r < 4; ++r) {
                float attn = __builtin_amdgcn_rcpf(1.0f + __expf(-(z[r] + zb)));
                s_scale[wid * 32 + t * 16 + g * 4 + r] = fmaf(alpha, attn, 1.0f);
            }
        }
    }
    // NO __syncthreads: scales are written and read by the SAME wave;
    // per-wave LDS ops execute in order.

    // ---- per-wave sweep of own 32 rows: out = PRV * (1 + alpha*attn) ----
    const float* s_wave = s_scale + wid * 32;
    f32x4* ob = reinterpret_cast<f32x4*>(out)
                + (size_t)blockIdx.x * 8192 + wid * 1024 + lane;
    #define PVUSE(IT, CNT) { \
        asm volatile("s_waitcnt vmcnt(" #CNT ")" : "+v"(pv##IT)); \
        float sc = s_wave[IT * 2 + hi]; \
        f32x4 v = pv##IT; \
        v[0] *= sc; v[1] *= sc; v[2] *= sc; v[3] *= sc; \
        ob[IT * 64] = v; }
    PVUSE(0, 15) PVUSE(1, 14) PVUSE(2, 13) PVUSE(3, 12)
    PVUSE(4, 11) PVUSE(5, 10) PVUSE(6, 9)  PVUSE(7, 8)
    PVUSE(8, 7)  PVUSE(9, 6)  PVUSE(10, 5) PVUSE(11, 4)
    PVUSE(12, 3) PVUSE(13, 2) PVUSE(14, 1) PVUSE(15, 0)
    #undef PVUSE
}

extern "C" void kernel_launch(void* const* d_in, const int* in_sizes, int n_in,
                              void* d_out, int out_size, void* d_ws, size_t ws_size,
                              hipStream_t stream) {
    const float* PRV    = (const float*)d_in[0];
    const float* PR     = (const float*)d_in[1];
    const float* c1     = (const float*)d_in[2];
    const float* gamma  = (const float*)d_in[3];
    const float* beta   = (const float*)d_in[4];
    const float* c2     = (const float*)d_in[5];
    const float* alphap = (const float*)d_in[6];
    float* out = (float*)d_out;

    unsigned short* Bpack = (unsigned short*)d_ws;            // 32 KB bf16 frags
    float* wsf   = (float*)((char*)d_ws + 32768);
    float* bias1 = wsf;          // 32
    float* E2    = wsf + 32;     // 128 (32 x float4)
    float* bias2 = wsf + 160;    // 1

    const int N = in_sizes[0] / C_DIM;

    hipLaunchKernelGGL(prep_kernel, dim3(64), dim3(256), 0, stream,
                       c1, c2, Bpack, bias1, E2, bias2);
    hipLaunchKernelGGL(fused_kernel, dim3(N / 256), dim3(512), 0, stream,
                       PRV, PR, Bpack, bias1, E2, bias2, gamma, beta, alphap, out);
}